// Round 1
// baseline (119.865 us; speedup 1.0000x reference)
//
#include <hip/hip_runtime.h>

// Problem constants (match reference)
#define FQ 8        // fields
#define NSEQ 2      // sequence fields
#define BQ 4096     // batch
#define LQ 50       // sequence length
#define VQ 100000   // vocab
#define EQ 64       // emb dim (== wavefront size)

// One block per batch element. 256 threads = 4 waves.
// Lane index == embedding element e. Each row gather = one coalesced 256B wave load.
__global__ __launch_bounds__(256, 4) void ffl_kernel(
    const int* __restrict__ x_seq,    // [NSEQ, B, L]
    const int* __restrict__ x_cat,    // [F-NSEQ, B, 1]
    const float* __restrict__ tables, // [F, F, V, E]
    float* __restrict__ out)          // [B]
{
    const int b    = blockIdx.x;
    const int tid  = threadIdx.x;
    const int lane = tid & 63;
    const int wave = tid >> 6;   // 0..3

    __shared__ float P[FQ][FQ][EQ];     // pooled embeddings, 16 KB
    __shared__ int   s_idx[NSEQ * LQ];  // sequence indices for this batch elem
    __shared__ int   c_idx[FQ - NSEQ];  // categorical indices
    __shared__ float partial[4];

    // Stage this batch element's indices into LDS (reused across 7 targets each).
    if (tid < NSEQ * LQ) {
        int a = tid / LQ;
        int l = tid - a * LQ;
        s_idx[tid] = x_seq[(a * BQ + b) * LQ + l];
    } else if (tid < NSEQ * LQ + (FQ - NSEQ)) {
        int a = tid - NSEQ * LQ;
        c_idx[a] = x_cat[a * BQ + b];
    }
    __syncthreads();

    // 56 ordered (a,t) pairs, a != t, distributed over 4 waves.
    for (int p = wave; p < FQ * (FQ - 1); p += 4) {
        int a = p / (FQ - 1);
        int r = p - a * (FQ - 1);
        int t = r + (r >= a ? 1 : 0);
        const float* __restrict__ tab = tables + (size_t)(a * FQ + t) * VQ * EQ;
        float acc;
        if (a < NSEQ) {
            acc = 0.0f;
            #pragma unroll 5
            for (int l = 0; l < LQ; ++l) {
                int v = s_idx[a * LQ + l];
                acc += tab[(size_t)v * EQ + lane];
            }
            acc *= (1.0f / LQ);   // mean over sequence axis
        } else {
            int v = c_idx[a - NSEQ];
            acc = tab[(size_t)v * EQ + lane];   // mean over length-1 axis
        }
        P[a][t][lane] = acc;   // lane-contiguous: conflict-free
    }
    __syncthreads();

    // 28 unordered pairs (a < c): sum of <P[a][c], P[c][a]>, 7 pairs per wave.
    float sum = 0.0f;
    {
        int p = 0;
        #pragma unroll
        for (int a = 0; a < FQ; ++a) {
            #pragma unroll
            for (int c = a + 1; c < FQ; ++c) {
                if ((p & 3) == wave)
                    sum += P[a][c][lane] * P[c][a][lane];
                ++p;
            }
        }
    }
    // Wave-level reduction over 64 lanes.
    #pragma unroll
    for (int off = 32; off > 0; off >>= 1)
        sum += __shfl_down(sum, off, 64);
    if (lane == 0) partial[wave] = sum;
    __syncthreads();
    if (tid == 0)
        out[b] = partial[0] + partial[1] + partial[2] + partial[3];
}

extern "C" void kernel_launch(void* const* d_in, const int* in_sizes, int n_in,
                              void* d_out, int out_size, void* d_ws, size_t ws_size,
                              hipStream_t stream) {
    const int*   x_seq  = (const int*)d_in[0];
    const int*   x_cat  = (const int*)d_in[1];
    const float* tables = (const float*)d_in[2];
    float*       out    = (float*)d_out;
    ffl_kernel<<<BQ, 256, 0, stream>>>(x_seq, x_cat, tables, out);
}

// Round 2
// 119.424 us; speedup vs baseline: 1.0037x; 1.0037x over previous
//
#include <hip/hip_runtime.h>

// Problem constants (match reference)
#define FQ 8        // fields
#define NSEQ 2      // sequence fields
#define BQ 4096     // batch
#define LQ 50       // sequence length
#define VQ 100000   // vocab
#define EQ 64       // emb dim (== wavefront size)
#define NPAIR 28    // unordered field pairs
#define CQ 4        // batch elems per block (1 per wave) -> many blocks/pair
#define CHUNKS (BQ / CQ)   // 1024 blocks per pair

// triu_indices(8, k=1) order
__device__ const int PA[NPAIR] = {0,0,0,0,0,0,0, 1,1,1,1,1,1, 2,2,2,2,2, 3,3,3,3, 4,4,4, 5,5, 6};
__device__ const int PB[NPAIR] = {1,2,3,4,5,6,7, 2,3,4,5,6,7, 3,4,5,6,7, 4,5,6,7, 5,6,7, 6,7, 7};

// Pair-major gather+pool+dot. Grid: pair*CHUNKS + chunk (pair-major dispatch
// order clusters all accesses to one 25.6MB table into a short time window so
// L3 (256MB) captures the ~2.35x row multiplicity of the sequence tables).
// Block: 256 threads = 4 waves; wave w handles batch elem b0+w; lane = emb elem.
template <bool ATOMIC>
__global__ __launch_bounds__(256) void pair_pool_dot(
    const int* __restrict__ x_seq,    // [NSEQ, B, L]
    const int* __restrict__ x_cat,    // [F-NSEQ, B, 1]
    const float* __restrict__ tables, // [F, F, V, E]
    float* __restrict__ partial,      // [NPAIR, B] (ws path) or out[B] (atomic path)
    float* __restrict__ out)          // unused in ws path
{
    const int blk   = blockIdx.x;
    const int pair  = blk / CHUNKS;
    const int chunk = blk - pair * CHUNKS;
    const int b0    = chunk * CQ;
    const int a = PA[pair], c = PB[pair];   // a < c always
    const int tid  = threadIdx.x;
    const int lane = tid & 63;
    const int wave = tid >> 6;
    const int b    = b0 + wave;

    __shared__ int sidx[2][CQ][LQ];   // staged sequence indices (broadcast reads)

    if (a < NSEQ) {
        if (tid < CQ * LQ) {
            int bl = tid / LQ, l = tid - bl * LQ;
            sidx[0][bl][l] = x_seq[((size_t)a * BQ + b0 + bl) * LQ + l];
        }
    }
    if (c < NSEQ) {   // only pair (0,1)
        if (tid < CQ * LQ) {
            int bl = tid / LQ, l = tid - bl * LQ;
            sidx[1][bl][l] = x_seq[((size_t)c * BQ + b0 + bl) * LQ + l];
        }
    }
    if (a < NSEQ || c < NSEQ) __syncthreads();

    const float* __restrict__ tab1 = tables + ((size_t)a * FQ + c) * VQ * EQ; // a -> c
    const float* __restrict__ tab2 = tables + ((size_t)c * FQ + a) * VQ * EQ; // c -> a

    float va, vc;
    if (a < NSEQ) {
        float acc = 0.0f;
        #pragma unroll 10
        for (int l = 0; l < LQ; ++l)
            acc += tab1[(size_t)sidx[0][wave][l] * EQ + lane];
        va = acc * (1.0f / LQ);
    } else {
        int v = x_cat[(size_t)(a - NSEQ) * BQ + b];
        va = tab1[(size_t)v * EQ + lane];
    }
    if (c < NSEQ) {
        float acc = 0.0f;
        #pragma unroll 10
        for (int l = 0; l < LQ; ++l)
            acc += tab2[(size_t)sidx[1][wave][l] * EQ + lane];
        vc = acc * (1.0f / LQ);
    } else {
        int v = x_cat[(size_t)(c - NSEQ) * BQ + b];
        vc = tab2[(size_t)v * EQ + lane];
    }

    float prod = va * vc;
    #pragma unroll
    for (int off = 32; off; off >>= 1)
        prod += __shfl_down(prod, off, 64);
    if (lane == 0) {
        if (ATOMIC) atomicAdd(&out[b], prod);
        else        partial[(size_t)pair * BQ + b] = prod;
    }
}

__global__ __launch_bounds__(256) void reduce_pairs(
    const float* __restrict__ partial, float* __restrict__ out)
{
    int b = blockIdx.x * 256 + threadIdx.x;
    if (b < BQ) {
        float s = 0.0f;
        #pragma unroll
        for (int p = 0; p < NPAIR; ++p)
            s += partial[(size_t)p * BQ + b];
        out[b] = s;
    }
}

__global__ __launch_bounds__(256) void zero_out(float* __restrict__ out)
{
    int b = blockIdx.x * 256 + threadIdx.x;
    if (b < BQ) out[b] = 0.0f;
}

extern "C" void kernel_launch(void* const* d_in, const int* in_sizes, int n_in,
                              void* d_out, int out_size, void* d_ws, size_t ws_size,
                              hipStream_t stream) {
    const int*   x_seq  = (const int*)d_in[0];
    const int*   x_cat  = (const int*)d_in[1];
    const float* tables = (const float*)d_in[2];
    float*       out    = (float*)d_out;

    const size_t need = (size_t)NPAIR * BQ * sizeof(float);
    if (ws_size >= need) {
        float* partial = (float*)d_ws;
        pair_pool_dot<false><<<NPAIR * CHUNKS, 256, 0, stream>>>(
            x_seq, x_cat, tables, partial, out);
        reduce_pairs<<<(BQ + 255) / 256, 256, 0, stream>>>(partial, out);
    } else {
        zero_out<<<(BQ + 255) / 256, 256, 0, stream>>>(out);
        pair_pool_dot<true><<<NPAIR * CHUNKS, 256, 0, stream>>>(
            x_seq, x_cat, tables, nullptr, out);
    }
}